// Round 1
// baseline (822.867 us; speedup 1.0000x reference)
//
#include <hip/hip_runtime.h>
#include <math.h>

// Problem constants (fixed by reference)
#define S_LEN   2048
#define HDIM    1024
#define NHEADS  16
#define DHEAD   64
#define BATCH   2
#define MROWS   (BATCH * S_LEN)   // 4096
#define STRIDE  4
#define LOCAL   8

// ---------------------------------------------------------------------------
// GEMM: C = A[M,K] @ W[K,N]  (row-major), M=4096, K=N=1024
// mode 0: scatter output to [B, NH, S, D]; optional scale sigmoid(*sig_ptr)/8
// mode 1: flat [M, N] output + bias
// Tile 128x128x16, 512 threads, 8x4 acc per thread.
// ---------------------------------------------------------------------------
#define TM 128
#define TN 128
#define TK 16

__global__ __launch_bounds__(512)
void gemm_kernel(const float* __restrict__ A, const float* __restrict__ W,
                 float* __restrict__ C, const float* __restrict__ bias,
                 const float* __restrict__ sig_ptr, int mode)
{
    __shared__ float As[TK][TM + 4];   // transposed A tile: As[k][m]
    __shared__ float Bs[TK][TN + 4];

    const int tid      = threadIdx.x;
    const int row_base = blockIdx.y * TM;
    const int col_base = blockIdx.x * TN;

    const int tx = tid & 31;   // col group: 4*tx
    const int ty = tid >> 5;   // row group: 8*ty

    float acc[8][4];
#pragma unroll
    for (int i = 0; i < 8; i++)
#pragma unroll
        for (int j = 0; j < 4; j++) acc[i][j] = 0.0f;

    for (int k0 = 0; k0 < HDIM; k0 += TK) {
        // --- stage A tile (128 rows x 16 k) transposed; 512 float4 chunks, 1/thread
        {
            const int c  = tid;
            const int m  = c >> 2;
            const int kq = c & 3;
            const float4 av = *reinterpret_cast<const float4*>(
                &A[(size_t)(row_base + m) * HDIM + k0 + kq * 4]);
            As[kq * 4 + 0][m] = av.x;
            As[kq * 4 + 1][m] = av.y;
            As[kq * 4 + 2][m] = av.z;
            As[kq * 4 + 3][m] = av.w;
        }
        // --- stage B tile (16 k x 128 cols); fully coalesced
        {
            const int c  = tid;
            const int kk = c >> 5;
            const int n4 = c & 31;
            const float4 bv = *reinterpret_cast<const float4*>(
                &W[(size_t)(k0 + kk) * HDIM + col_base + n4 * 4]);
            *reinterpret_cast<float4*>(&Bs[kk][n4 * 4]) = bv;
        }
        __syncthreads();

#pragma unroll
        for (int kk = 0; kk < TK; kk++) {
            const float4 a0 = *reinterpret_cast<const float4*>(&As[kk][8 * ty]);
            const float4 a1 = *reinterpret_cast<const float4*>(&As[kk][8 * ty + 4]);
            const float4 b  = *reinterpret_cast<const float4*>(&Bs[kk][4 * tx]);
            const float av[8] = {a0.x, a0.y, a0.z, a0.w, a1.x, a1.y, a1.z, a1.w};
            const float bv[4] = {b.x, b.y, b.z, b.w};
#pragma unroll
            for (int i = 0; i < 8; i++)
#pragma unroll
                for (int j = 0; j < 4; j++)
                    acc[i][j] = fmaf(av[i], bv[j], acc[i][j]);
        }
        __syncthreads();
    }

    // --- epilogue
    float scale = 1.0f;
    if (mode == 0 && sig_ptr != nullptr) {
        const float u = *sig_ptr;
        scale = (1.0f / (1.0f + expf(-u))) * 0.125f;  // sigmoid(phi) * 1/sqrt(D)
    }
    const int cbase = col_base + 4 * tx;

    if (mode == 0) {
        const int h = cbase >> 6;
        const int d = cbase & 63;   // 4-chunk never crosses head boundary
#pragma unroll
        for (int i = 0; i < 8; i++) {
            const int r = row_base + 8 * ty + i;
            const int b = r >> 11;            // / S_LEN
            const int s = r & (S_LEN - 1);
            float4 v = make_float4(acc[i][0] * scale, acc[i][1] * scale,
                                   acc[i][2] * scale, acc[i][3] * scale);
            *reinterpret_cast<float4*>(
                &C[((size_t)((b * NHEADS + h) * S_LEN + s)) * DHEAD + d]) = v;
        }
    } else {
        const float4 bv4 = *reinterpret_cast<const float4*>(&bias[cbase]);
#pragma unroll
        for (int i = 0; i < 8; i++) {
            const int r = row_base + 8 * ty + i;
            float4 v = make_float4(acc[i][0] + bv4.x, acc[i][1] + bv4.y,
                                   acc[i][2] + bv4.z, acc[i][3] + bv4.w);
            *reinterpret_cast<float4*>(&C[(size_t)r * HDIM + cbase]) = v;
        }
    }
}

// ---------------------------------------------------------------------------
// Sparse ("strided") flash attention, fp32.
// One block = 256 threads = 256 consecutive q rows of one (b, h).
// Phase 1: 512 strided keys (j % 4 == 0), staged in LDS tiles of 64,
//          broadcast LDS reads (all lanes same address -> conflict-free).
// Phase 2: local band |i-j| <= 8 with j % 4 != 0, straight from global/L2.
// Online softmax with defer-max (rescale only when score exceeds m+8).
// ---------------------------------------------------------------------------
#define KT 64   // keys per phase-1 tile

__global__ __launch_bounds__(256)
void attn_kernel(const float* __restrict__ Q, const float* __restrict__ K,
                 const float* __restrict__ V, float* __restrict__ O)
{
    __shared__ float Ks[KT][DHEAD];
    __shared__ float Vs[KT][DHEAD];

    const int tid = threadIdx.x;
    const int bx  = blockIdx.x;
    const int qt  = bx & 7;           // S / 256 = 8 q-tiles
    const int h   = (bx >> 3) & 15;
    const int b   = bx >> 7;

    const int s = qt * 256 + tid;     // this thread's query row

    const float* __restrict__ Kbh = K + (size_t)((b * NHEADS + h) * S_LEN) * DHEAD;
    const float* __restrict__ Vbh = V + (size_t)((b * NHEADS + h) * S_LEN) * DHEAD;
    const float* __restrict__ qrow =
        Q + ((size_t)((b * NHEADS + h) * S_LEN + s)) * DHEAD;

    float q[DHEAD];
#pragma unroll
    for (int d4 = 0; d4 < DHEAD / 4; d4++) {
        const float4 v = *reinterpret_cast<const float4*>(&qrow[d4 * 4]);
        q[d4 * 4 + 0] = v.x; q[d4 * 4 + 1] = v.y;
        q[d4 * 4 + 2] = v.z; q[d4 * 4 + 3] = v.w;
    }

    float o[DHEAD];
#pragma unroll
    for (int d = 0; d < DHEAD; d++) o[d] = 0.0f;
    float m = -1e30f;
    float l = 0.0f;

    // ---------------- phase 1: strided keys ----------------
    for (int t0 = 0; t0 < S_LEN / STRIDE; t0 += KT) {
        // stage KT keys of K and V: 1024 float4 each side, 4 per thread
#pragma unroll
        for (int i = 0; i < (KT * DHEAD / 4) / 256; i++) {
            const int c   = tid + i * 256;
            const int key = c >> 4;
            const int dq  = (c & 15) * 4;
            const int j   = (t0 + key) * STRIDE;
            *reinterpret_cast<float4*>(&Ks[key][dq]) =
                *reinterpret_cast<const float4*>(&Kbh[(size_t)j * DHEAD + dq]);
            *reinterpret_cast<float4*>(&Vs[key][dq]) =
                *reinterpret_cast<const float4*>(&Vbh[(size_t)j * DHEAD + dq]);
        }
        __syncthreads();

#pragma unroll 2
        for (int kk = 0; kk < KT; kk++) {
            float s0 = 0.f, s1 = 0.f, s2 = 0.f, s3 = 0.f;
#pragma unroll
            for (int d = 0; d < DHEAD; d += 4) {
                const float4 kv = *reinterpret_cast<const float4*>(&Ks[kk][d]);
                s0 = fmaf(q[d + 0], kv.x, s0);
                s1 = fmaf(q[d + 1], kv.y, s1);
                s2 = fmaf(q[d + 2], kv.z, s2);
                s3 = fmaf(q[d + 3], kv.w, s3);
            }
            const float sc = (s0 + s1) + (s2 + s3);
            if (sc > m + 8.0f) {             // defer-max: rare rescale
                const float f = __expf(m - sc);
                m = sc;
                l *= f;
#pragma unroll
                for (int d = 0; d < DHEAD; d++) o[d] *= f;
            }
            const float p = __expf(sc - m);  // bounded by e^8
            l += p;
#pragma unroll
            for (int d = 0; d < DHEAD; d += 4) {
                const float4 vv = *reinterpret_cast<const float4*>(&Vs[kk][d]);
                o[d + 0] = fmaf(p, vv.x, o[d + 0]);
                o[d + 1] = fmaf(p, vv.y, o[d + 1]);
                o[d + 2] = fmaf(p, vv.z, o[d + 2]);
                o[d + 3] = fmaf(p, vv.w, o[d + 3]);
            }
        }
        __syncthreads();
    }

    // ---------------- phase 2: local band (j % 4 != 0) ----------------
    for (int dj = -LOCAL; dj <= LOCAL; dj++) {
        const int j = s + dj;
        if (j < 0 || j >= S_LEN || ((j & 3) == 0)) continue;
        const float* __restrict__ krow = &Kbh[(size_t)j * DHEAD];
        float s0 = 0.f, s1 = 0.f, s2 = 0.f, s3 = 0.f;
#pragma unroll
        for (int d = 0; d < DHEAD; d += 4) {
            const float4 kv = *reinterpret_cast<const float4*>(&krow[d]);
            s0 = fmaf(q[d + 0], kv.x, s0);
            s1 = fmaf(q[d + 1], kv.y, s1);
            s2 = fmaf(q[d + 2], kv.z, s2);
            s3 = fmaf(q[d + 3], kv.w, s3);
        }
        const float sc = (s0 + s1) + (s2 + s3);
        if (sc > m + 8.0f) {
            const float f = __expf(m - sc);
            m = sc;
            l *= f;
#pragma unroll
            for (int d = 0; d < DHEAD; d++) o[d] *= f;
        }
        const float p = __expf(sc - m);
        l += p;
        const float* __restrict__ vrow = &Vbh[(size_t)j * DHEAD];
#pragma unroll
        for (int d = 0; d < DHEAD; d += 4) {
            const float4 vv = *reinterpret_cast<const float4*>(&vrow[d]);
            o[d + 0] = fmaf(p, vv.x, o[d + 0]);
            o[d + 1] = fmaf(p, vv.y, o[d + 1]);
            o[d + 2] = fmaf(p, vv.z, o[d + 2]);
            o[d + 3] = fmaf(p, vv.w, o[d + 3]);
        }
    }

    // ---------------- finalize: O[b, s, h*64 + d] = o / l ----------------
    const float inv = 1.0f / l;
    float* __restrict__ orow = O + ((size_t)(b * S_LEN + s)) * HDIM + h * DHEAD;
#pragma unroll
    for (int d4 = 0; d4 < DHEAD / 4; d4++) {
        float4 v = make_float4(o[d4 * 4 + 0] * inv, o[d4 * 4 + 1] * inv,
                               o[d4 * 4 + 2] * inv, o[d4 * 4 + 3] * inv);
        *reinterpret_cast<float4*>(&orow[d4 * 4]) = v;
    }
}

// ---------------------------------------------------------------------------
// Launch: 3 projection GEMMs -> sparse attention -> output GEMM (+bias).
// Workspace layout (fp32): Q | K | V | attn_out, 4*16 MB = 64 MB required.
// ---------------------------------------------------------------------------
extern "C" void kernel_launch(void* const* d_in, const int* in_sizes, int n_in,
                              void* d_out, int out_size, void* d_ws, size_t ws_size,
                              hipStream_t stream)
{
    const float* x      = (const float*)d_in[0];
    const float* q_w    = (const float*)d_in[1];
    const float* k_w    = (const float*)d_in[2];
    const float* v_w    = (const float*)d_in[3];
    const float* o_w    = (const float*)d_in[4];
    const float* o_b    = (const float*)d_in[5];
    const float* uscale = (const float*)d_in[6];
    float* out = (float*)d_out;

    const size_t NTOK = (size_t)MROWS * HDIM;  // 4,194,304 elements
    float* ws = (float*)d_ws;
    float* Qb = ws;
    float* Kb = Qb + NTOK;
    float* Vb = Kb + NTOK;
    float* Ob = Vb + NTOK;   // attention output, [B, S, H] flat

    const dim3 gblk(512);
    const dim3 ggrid(HDIM / TN, MROWS / TM);   // (8, 32) = 256 blocks

    gemm_kernel<<<ggrid, gblk, 0, stream>>>(x, q_w, Qb, nullptr, uscale, 0);
    gemm_kernel<<<ggrid, gblk, 0, stream>>>(x, k_w, Kb, nullptr, nullptr, 0);
    gemm_kernel<<<ggrid, gblk, 0, stream>>>(x, v_w, Vb, nullptr, nullptr, 0);

    attn_kernel<<<dim3(BATCH * NHEADS * (S_LEN / 256)), dim3(256), 0, stream>>>(
        Qb, Kb, Vb, Ob);

    gemm_kernel<<<ggrid, gblk, 0, stream>>>(Ob, o_w, out, o_b, nullptr, 1);
}

// Round 2
// 580.672 us; speedup vs baseline: 1.4171x; 1.4171x over previous
//
#include <hip/hip_runtime.h>
#include <math.h>

// Problem constants (fixed by reference)
#define S_LEN   2048
#define HDIM    1024
#define NHEADS  16
#define DHEAD   64
#define BATCH   2
#define MROWS   (BATCH * S_LEN)   // 4096
#define STRIDE  4
#define LOCAL   8

typedef __attribute__((ext_vector_type(8))) short s16x8;   // 8 bf16 (4 VGPRs)
typedef __attribute__((ext_vector_type(4))) float f32x4;

// ---- fp32 -> bf16 round-to-nearest-even, and back --------------------------
__device__ __forceinline__ unsigned short bf16_rn(float x) {
    unsigned u = __float_as_uint(x);
    unsigned r = (u + 0x7FFFu + ((u >> 16) & 1u)) >> 16;
    return (unsigned short)r;
}
__device__ __forceinline__ float bf16_f(unsigned short h) {
    return __uint_as_float(((unsigned)h) << 16);
}

// ---- async global->LDS, 16B per lane (dest = wave base + lane*16) ----------
__device__ __forceinline__ void gll16(const void* g, void* l) {
    __builtin_amdgcn_global_load_lds(
        (const __attribute__((address_space(1))) void*)g,
        (__attribute__((address_space(3))) void*)l, 16, 0, 0);
}

// ---------------------------------------------------------------------------
// Prep 1: elementwise fp32 -> (bf16 hi, bf16 lo) split. 4 elems/thread.
// ---------------------------------------------------------------------------
__global__ __launch_bounds__(256)
void split_kernel(const float* __restrict__ src, unsigned short* __restrict__ hi,
                  unsigned short* __restrict__ lo, int n4)
{
    const int i = blockIdx.x * 256 + threadIdx.x;
    if (i >= n4) return;
    const float4 v = reinterpret_cast<const float4*>(src)[i];
    const float vv[4] = {v.x, v.y, v.z, v.w};
    unsigned short hh[4], ll[4];
#pragma unroll
    for (int j = 0; j < 4; j++) {
        hh[j] = bf16_rn(vv[j]);
        ll[j] = bf16_rn(vv[j] - bf16_f(hh[j]));
    }
    reinterpret_cast<ushort4*>(hi)[i] = make_ushort4(hh[0], hh[1], hh[2], hh[3]);
    reinterpret_cast<ushort4*>(lo)[i] = make_ushort4(ll[0], ll[1], ll[2], ll[3]);
}

// ---------------------------------------------------------------------------
// Prep 2: weight [K][N] fp32 -> transposed bf16 hi/lo [N][K], 32x32 LDS tiles.
// ---------------------------------------------------------------------------
__global__ __launch_bounds__(256)
void wsplit_kernel(const float* __restrict__ W,
                   unsigned short* __restrict__ hiT, unsigned short* __restrict__ loT)
{
    __shared__ unsigned short his[32][33];
    __shared__ unsigned short los[32][33];
    const int t  = threadIdx.x;
    const int kb = blockIdx.x * 32;
    const int nb = blockIdx.y * 32;
    {
        const int row = t >> 3;          // k within tile
        const int c4  = (t & 7) * 4;     // n within tile
        const float4 v = *reinterpret_cast<const float4*>(
            &W[(size_t)(kb + row) * HDIM + nb + c4]);
        const float vv[4] = {v.x, v.y, v.z, v.w};
#pragma unroll
        for (int j = 0; j < 4; j++) {
            const unsigned short h = bf16_rn(vv[j]);
            his[row][c4 + j] = h;
            los[row][c4 + j] = bf16_rn(vv[j] - bf16_f(h));
        }
    }
    __syncthreads();
    {
        const int n  = t >> 3;
        const int k4 = (t & 7) * 4;
        const ushort4 h = make_ushort4(his[k4][n], his[k4+1][n], his[k4+2][n], his[k4+3][n]);
        const ushort4 l = make_ushort4(los[k4][n], los[k4+1][n], los[k4+2][n], los[k4+3][n]);
        *reinterpret_cast<ushort4*>(&hiT[(size_t)(nb + n) * HDIM + kb + k4]) = h;
        *reinterpret_cast<ushort4*>(&loT[(size_t)(nb + n) * HDIM + kb + k4]) = l;
    }
}

// ---------------------------------------------------------------------------
// MFMA GEMM with 3-term bf16 split: C = Ahi@Whi + Ahi@Wlo + Alo@Whi.
// A: [4096][1024] bf16 (hi/lo). W given TRANSPOSED: [N][K] bf16 (hi/lo).
// Virtual K = 3*1024, BK=64. Tile 128x128, 4 waves (2x2), 4x4 frags/wave.
// LDS double-buffered; global_load_lds w/ pre-swizzled source (T2 swizzle).
// mode 0: scatter to [B,NH,S,D] with optional sigmoid(*sig)/8 scale.
// mode 1: flat [M][N] + bias.
// ---------------------------------------------------------------------------
__global__ __launch_bounds__(256)
void gemm_mfma(const unsigned short* __restrict__ Ahi, const unsigned short* __restrict__ Alo,
               const unsigned short* __restrict__ WhiT, const unsigned short* __restrict__ WloT,
               float* __restrict__ C, const float* __restrict__ bias,
               const float* __restrict__ sig_ptr, int mode)
{
    __shared__ unsigned short As[2][128 * 64];
    __shared__ unsigned short Bs[2][128 * 64];

    const int tid  = threadIdx.x;
    const int lane = tid & 63;
    const int w    = tid >> 6;
    const int wr   = w >> 1;      // wave row (0..1) -> 64 rows each
    const int wc   = w & 1;       // wave col (0..1) -> 64 cols each
    const int row_base = blockIdx.y * 128;
    const int col_base = blockIdx.x * 128;

    f32x4 acc[4][4] = {};

    // stage one 128x64 A-tile + 128x64 B-tile (bf16) into LDS buffer b.
    // LDS dest is linear in chunk id (global_load_lds constraint); the
    // global source is pre-swizzled so swizzled reads land correctly.
    auto stage = [&](int b, const unsigned short* Ap, const unsigned short* Bp, int k0) {
#pragma unroll
        for (int r = 0; r < 4; ++r) {
            const int c    = tid + r * 256;      // chunk id 0..1023
            const int row  = c >> 3;             // tile row 0..127
            const int c7   = c & 7;              // 16B chunk within 128B row
            const int goff = ((c7 * 16) ^ ((row & 7) << 4)) >> 1;  // bf16 elems
            gll16(Ap + (size_t)(row_base + row) * HDIM + k0 + goff, &As[b][c * 8]);
            gll16(Bp + (size_t)(col_base + row) * HDIM + k0 + goff, &Bs[b][c * 8]);
        }
    };

    auto compute = [&](int b) {
#pragma unroll
        for (int kk = 0; kk < 2; ++kk) {
            // byte col offset within 128B row, then XOR-swizzle by row&7
            const int sofs = (kk * 64 + ((lane >> 4) << 4)) ^ ((lane & 7) << 4);
            s16x8 af[4], bfr[4];
#pragma unroll
            for (int mi = 0; mi < 4; ++mi) {
                const int row = wr * 64 + mi * 16 + (lane & 15);
                af[mi] = *reinterpret_cast<const s16x8*>(
                    reinterpret_cast<const char*>(&As[b][row * 64]) + sofs);
            }
#pragma unroll
            for (int ni = 0; ni < 4; ++ni) {
                const int row = wc * 64 + ni * 16 + (lane & 15);
                bfr[ni] = *reinterpret_cast<const s16x8*>(
                    reinterpret_cast<const char*>(&Bs[b][row * 64]) + sofs);
            }
#pragma unroll
            for (int mi = 0; mi < 4; ++mi)
#pragma unroll
                for (int ni = 0; ni < 4; ++ni)
                    acc[mi][ni] = __builtin_amdgcn_mfma_f32_16x16x32_bf16(
                        af[mi], bfr[ni], acc[mi][ni], 0, 0, 0);
        }
    };

    // ---- 2-phase pipelined K-loop: 48 virtual steps (3 variants x 16) ----
    stage(0, Ahi, WhiT, 0);
    __syncthreads();
    int buf = 0;
#pragma unroll 1
    for (int kt = 0; kt < 48; ++kt) {
        if (kt + 1 < 48) {
            const int nx = kt + 1;
            const int v  = nx >> 4;
            const int k0 = (nx & 15) * 64;
            const unsigned short* Ap = (v == 2) ? Alo  : Ahi;
            const unsigned short* Bp = (v == 1) ? WloT : WhiT;
            stage(buf ^ 1, Ap, Bp, k0);
        }
        compute(buf);
        __syncthreads();          // drains prefetch vmcnt + frees buf
        buf ^= 1;
    }

    // ---- epilogue ----
    float scale = 1.0f;
    if (mode == 0 && sig_ptr != nullptr) {
        const float u = *sig_ptr;
        scale = (1.0f / (1.0f + __expf(-u))) * 0.125f;  // sigmoid(phi)/sqrt(D)
    }
#pragma unroll
    for (int mi = 0; mi < 4; ++mi) {
#pragma unroll
        for (int ni = 0; ni < 4; ++ni) {
            const int gr0 = row_base + wr * 64 + mi * 16 + ((lane >> 4) << 2);
            const int gc  = col_base + wc * 64 + ni * 16 + (lane & 15);
            if (mode == 0) {
                const int h = gc >> 6, d = gc & 63;
#pragma unroll
                for (int r = 0; r < 4; ++r) {
                    const int gr = gr0 + r;
                    const int bb = gr >> 11, s = gr & (S_LEN - 1);
                    C[((size_t)((bb * NHEADS + h) * S_LEN + s)) * DHEAD + d] =
                        acc[mi][ni][r] * scale;
                }
            } else {
                const float bv = bias[gc];
#pragma unroll
                for (int r = 0; r < 4; ++r)
                    C[(size_t)(gr0 + r) * HDIM + gc] = acc[mi][ni][r] + bv;
            }
        }
    }
}

// ---------------------------------------------------------------------------
// Sparse ("strided") flash attention, fp32, double-buffered LDS staging via
// global_load_lds. One block = 256 threads = 256 q rows of one (b,h).
// Output written directly as bf16 hi/lo split (feeds the final MFMA GEMM).
// ---------------------------------------------------------------------------
#define KT 64   // keys per phase-1 tile

__global__ __launch_bounds__(256)
void attn_kernel(const float* __restrict__ Q, const float* __restrict__ K,
                 const float* __restrict__ V,
                 unsigned short* __restrict__ Ohi, unsigned short* __restrict__ Olo)
{
    __shared__ float Ks[2][KT * DHEAD];
    __shared__ float Vs[2][KT * DHEAD];

    const int tid = threadIdx.x;
    const int bx  = blockIdx.x;
    const int qt  = bx & 7;
    const int h   = (bx >> 3) & 15;
    const int b   = bx >> 7;
    const int s   = qt * 256 + tid;

    const float* __restrict__ Kbh = K + (size_t)((b * NHEADS + h) * S_LEN) * DHEAD;
    const float* __restrict__ Vbh = V + (size_t)((b * NHEADS + h) * S_LEN) * DHEAD;
    const float* __restrict__ qrow =
        Q + ((size_t)((b * NHEADS + h) * S_LEN + s)) * DHEAD;

    float q[DHEAD];
#pragma unroll
    for (int d4 = 0; d4 < DHEAD / 4; d4++) {
        const float4 v = *reinterpret_cast<const float4*>(&qrow[d4 * 4]);
        q[d4*4+0] = v.x; q[d4*4+1] = v.y; q[d4*4+2] = v.z; q[d4*4+3] = v.w;
    }

    float o[DHEAD];
#pragma unroll
    for (int d = 0; d < DHEAD; d++) o[d] = 0.0f;
    float m = -1e30f;
    float l = 0.0f;

    // stage 64 strided keys of K and V (16KB each) into buffer bsel.
    // chunk c = 16B = 4 floats; LDS layout [key][d] is linear in c.
    auto stage = [&](int bsel, int t0) {
#pragma unroll
        for (int r = 0; r < 4; ++r) {
            const int c   = tid + r * 256;
            const int key = c >> 4;
            const int ch  = c & 15;
            const size_t goff = (size_t)((t0 + key) * STRIDE) * DHEAD + ch * 4;
            gll16(Kbh + goff, &Ks[bsel][c * 4]);
            gll16(Vbh + goff, &Vs[bsel][c * 4]);
        }
    };

    // ---------------- phase 1: strided keys, 2-phase pipeline ----------------
    stage(0, 0);
    __syncthreads();
    int buf = 0;
#pragma unroll 1
    for (int t0 = 0; t0 < S_LEN / STRIDE; t0 += KT) {
        if (t0 + KT < S_LEN / STRIDE) stage(buf ^ 1, t0 + KT);

#pragma unroll 2
        for (int kk = 0; kk < KT; kk++) {
            float s0 = 0.f, s1 = 0.f, s2 = 0.f, s3 = 0.f;
            const float* __restrict__ krow = &Ks[buf][kk * DHEAD];
#pragma unroll
            for (int d = 0; d < DHEAD; d += 4) {
                const float4 kv = *reinterpret_cast<const float4*>(&krow[d]);
                s0 = fmaf(q[d+0], kv.x, s0);
                s1 = fmaf(q[d+1], kv.y, s1);
                s2 = fmaf(q[d+2], kv.z, s2);
                s3 = fmaf(q[d+3], kv.w, s3);
            }
            const float sc = (s0 + s1) + (s2 + s3);
            if (sc > m + 8.0f) {             // defer-max: rare rescale
                const float f = __expf(m - sc);
                m = sc;
                l *= f;
#pragma unroll
                for (int d = 0; d < DHEAD; d++) o[d] *= f;
            }
            const float p = __expf(sc - m);
            l += p;
            const float* __restrict__ vrow = &Vs[buf][kk * DHEAD];
#pragma unroll
            for (int d = 0; d < DHEAD; d += 4) {
                const float4 vv = *reinterpret_cast<const float4*>(&vrow[d]);
                o[d+0] = fmaf(p, vv.x, o[d+0]);
                o[d+1] = fmaf(p, vv.y, o[d+1]);
                o[d+2] = fmaf(p, vv.z, o[d+2]);
                o[d+3] = fmaf(p, vv.w, o[d+3]);
            }
        }
        __syncthreads();
        buf ^= 1;
    }

    // ---------------- phase 2: local band (j % 4 != 0) ----------------
    for (int dj = -LOCAL; dj <= LOCAL; dj++) {
        const int j = s + dj;
        if (j < 0 || j >= S_LEN || ((j & 3) == 0)) continue;
        const float* __restrict__ krow = &Kbh[(size_t)j * DHEAD];
        float s0 = 0.f, s1 = 0.f, s2 = 0.f, s3 = 0.f;
#pragma unroll
        for (int d = 0; d < DHEAD; d += 4) {
            const float4 kv = *reinterpret_cast<const float4*>(&krow[d]);
            s0 = fmaf(q[d+0], kv.x, s0);
            s1 = fmaf(q[d+1], kv.y, s1);
            s2 = fmaf(q[d+2], kv.z, s2);
            s3 = fmaf(q[d+3], kv.w, s3);
        }
        const float sc = (s0 + s1) + (s2 + s3);
        if (sc > m + 8.0f) {
            const float f = __expf(m - sc);
            m = sc;
            l *= f;
#pragma unroll
            for (int d = 0; d < DHEAD; d++) o[d] *= f;
        }
        const float p = __expf(sc - m);
        l += p;
        const float* __restrict__ vrow = &Vbh[(size_t)j * DHEAD];
#pragma unroll
        for (int d = 0; d < DHEAD; d += 4) {
            const float4 vv = *reinterpret_cast<const float4*>(&vrow[d]);
            o[d+0] = fmaf(p, vv.x, o[d+0]);
            o[d+1] = fmaf(p, vv.y, o[d+1]);
            o[d+2] = fmaf(p, vv.z, o[d+2]);
            o[d+3] = fmaf(p, vv.w, o[d+3]);
        }
    }

    // ---------------- finalize: bf16 hi/lo split to [B,S,H] ----------------
    const float inv = 1.0f / l;
    const size_t obase = ((size_t)(b * S_LEN + s)) * HDIM + h * DHEAD;
#pragma unroll
    for (int d4 = 0; d4 < DHEAD / 4; ++d4) {
        unsigned short hh[4], ll[4];
#pragma unroll
        for (int j = 0; j < 4; ++j) {
            const float val = o[d4 * 4 + j] * inv;
            hh[j] = bf16_rn(val);
            ll[j] = bf16_rn(val - bf16_f(hh[j]));
        }
        *reinterpret_cast<ushort4*>(&Ohi[obase + d4 * 4]) =
            make_ushort4(hh[0], hh[1], hh[2], hh[3]);
        *reinterpret_cast<ushort4*>(&Olo[obase + d4 * 4]) =
            make_ushort4(ll[0], ll[1], ll[2], ll[3]);
    }
}

// ---------------------------------------------------------------------------
// Pipeline: split x -> split+transpose weights -> 3 MFMA GEMMs (QKV) ->
// fp32 sparse attention (emits bf16 hi/lo) -> MFMA GEMM (+bias) to d_out.
// Workspace (80 MB): QKV fp32 48MB | x hi/lo 16MB (reused as attn-out hi/lo)
//                    | 4 weights hi/lo transposed 16MB.
// ---------------------------------------------------------------------------
extern "C" void kernel_launch(void* const* d_in, const int* in_sizes, int n_in,
                              void* d_out, int out_size, void* d_ws, size_t ws_size,
                              hipStream_t stream)
{
    const float* x      = (const float*)d_in[0];
    const float* q_w    = (const float*)d_in[1];
    const float* k_w    = (const float*)d_in[2];
    const float* v_w    = (const float*)d_in[3];
    const float* o_w    = (const float*)d_in[4];
    const float* o_b    = (const float*)d_in[5];
    const float* uscale = (const float*)d_in[6];
    float* out = (float*)d_out;

    const size_t MB = (size_t)1 << 20;
    char* ws = (char*)d_ws;
    float* Qb = (float*)(ws);
    float* Kb = (float*)(ws + 16 * MB);
    float* Vb = (float*)(ws + 32 * MB);
    unsigned short* Xhi = (unsigned short*)(ws + 48 * MB);  // also attn-out hi
    unsigned short* Xlo = (unsigned short*)(ws + 56 * MB);  // also attn-out lo
    unsigned short* Wq_h = (unsigned short*)(ws + 64 * MB);
    unsigned short* Wq_l = (unsigned short*)(ws + 66 * MB);
    unsigned short* Wk_h = (unsigned short*)(ws + 68 * MB);
    unsigned short* Wk_l = (unsigned short*)(ws + 70 * MB);
    unsigned short* Wv_h = (unsigned short*)(ws + 72 * MB);
    unsigned short* Wv_l = (unsigned short*)(ws + 74 * MB);
    unsigned short* Wo_h = (unsigned short*)(ws + 76 * MB);
    unsigned short* Wo_l = (unsigned short*)(ws + 78 * MB);

    // prep
    split_kernel<<<dim3(MROWS * HDIM / 4 / 256), dim3(256), 0, stream>>>(
        x, Xhi, Xlo, MROWS * HDIM / 4);
    const dim3 wtg(HDIM / 32, HDIM / 32);
    wsplit_kernel<<<wtg, dim3(256), 0, stream>>>(q_w, Wq_h, Wq_l);
    wsplit_kernel<<<wtg, dim3(256), 0, stream>>>(k_w, Wk_h, Wk_l);
    wsplit_kernel<<<wtg, dim3(256), 0, stream>>>(v_w, Wv_h, Wv_l);
    wsplit_kernel<<<wtg, dim3(256), 0, stream>>>(o_w, Wo_h, Wo_l);

    // projections
    const dim3 gg(HDIM / 128, MROWS / 128);   // (8, 32)
    gemm_mfma<<<gg, dim3(256), 0, stream>>>(Xhi, Xlo, Wq_h, Wq_l, Qb, nullptr, uscale, 0);
    gemm_mfma<<<gg, dim3(256), 0, stream>>>(Xhi, Xlo, Wk_h, Wk_l, Kb, nullptr, nullptr, 0);
    gemm_mfma<<<gg, dim3(256), 0, stream>>>(Xhi, Xlo, Wv_h, Wv_l, Vb, nullptr, nullptr, 0);

    // attention (reads Q/K/V, overwrites Xhi/Xlo with its own hi/lo output)
    attn_kernel<<<dim3(BATCH * NHEADS * (S_LEN / 256)), dim3(256), 0, stream>>>(
        Qb, Kb, Vb, Xhi, Xlo);

    // output projection + bias
    gemm_mfma<<<gg, dim3(256), 0, stream>>>(Xhi, Xlo, Wo_h, Wo_l, out, o_b, nullptr, 1);
}